// Round 3
// baseline (460.570 us; speedup 1.0000x reference)
//
#include <hip/hip_runtime.h>
#include <math.h>

// ---------------------------------------------------------------------------
// SLAY sampled-softmax loss on MI355X.
// H=4 heads, D=128, P=16 anchors, M=32 features, R=2 quad nodes, E=512.
// B=512, S=64, K=5, L=32768 labels, VOCAB=100000.
//
// Decomposition (never materialize phi matrices):
//   phi[n,(r,h,p,m)] = poly[n,h,p] * prf[r,n,h,m]
//   Z[r,h,p,m]  = sum_l poly_W[l,h,p]*prf_W[r,l,h,m]   (register-blocked LDS matmul)
//   denom[b]    = sum_f phi_q[b,f]*Z[f]
//   nums[b,k]   = sum_h (poly_W.poly_q)[h] * sum_r (prf_W.prf_q)[r,h]   (factorized)
//
// R2 changes: 4 dispatches total (setup / embed+feat / labels / denom+loss).
// k_labels Z-matmul register-blocked: thread owns 4p x 4m (16 acc), one wave
// covers the full Z tile, waves split q; LDS cyc/FMA drops ~3x.
// ---------------------------------------------------------------------------

namespace {
constexpr double Cq  = 2.0 + 1e-6;
constexpr double QN0 = 0.5857864376269049  / Cq;   // laggauss(2) nodes / C
constexpr double QN1 = 3.414213562373095   / Cq;
constexpr double QW0 = 0.8535533905932738  / Cq;   // laggauss(2) weights / C
constexpr double QW1 = 0.14644660940672624 / Cq;

// workspace float offsets
constexpr size_t OFF_POLYQ = 0;                    // 512*4*16   [b][h][p]
constexpr size_t OFF_PRFQ  = 32768;                // 512*2*4*32 [b][r][h][m]
constexpr size_t OFF_Z     = OFF_PRFQ + 131072;    // 4096       [r][h][p][m]
constexpr size_t OFF_ANCT  = OFF_Z + 4096;         // 128*16 anchors transposed [d][p]
constexpr size_t OFF_SLOT  = OFF_ANCT + 2048;      // 32768 ints: label -> slot or -1
constexpr size_t OFF_FEAT  = OFF_SLOT + 32768;     // 2560*4*80  [slot][h][16 poly+64 prf]
}

// Single-pass raw accumulation: sumsq + 16 poly dots + 64 prf dots over d=0..127.
// Coefficient loads are wave-uniform -> scalar/broadcast loads.
__device__ __forceinline__ void accum_feat(const float* __restrict__ x, long xstride,
                                           const float* __restrict__ anct,
                                           const float* __restrict__ omega, int h,
                                           float& sumsq, float poly[16], float prf[64])
{
    for (int d = 0; d < 128; ++d) {
        float xv = x[(long)d * xstride];
        sumsq = fmaf(xv, xv, sumsq);
        const float4* a4 = (const float4*)(anct + d * 16);
#pragma unroll
        for (int j = 0; j < 4; ++j) {
            float4 a = a4[j];
            poly[4*j+0] = fmaf(xv, a.x, poly[4*j+0]);
            poly[4*j+1] = fmaf(xv, a.y, poly[4*j+1]);
            poly[4*j+2] = fmaf(xv, a.z, poly[4*j+2]);
            poly[4*j+3] = fmaf(xv, a.w, poly[4*j+3]);
        }
#pragma unroll
        for (int r = 0; r < 2; ++r) {
            const float4* w4 = (const float4*)(omega + (((r*4 + h)*128 + d) * 32));
#pragma unroll
            for (int j = 0; j < 8; ++j) {
                float4 w = w4[j];
                prf[r*32 + 4*j+0] = fmaf(xv, w.x, prf[r*32 + 4*j+0]);
                prf[r*32 + 4*j+1] = fmaf(xv, w.y, prf[r*32 + 4*j+1]);
                prf[r*32 + 4*j+2] = fmaf(xv, w.z, prf[r*32 + 4*j+2]);
                prf[r*32 + 4*j+3] = fmaf(xv, w.w, prf[r*32 + 4*j+3]);
            }
        }
    }
}

__device__ __forceinline__ void finalize_feat(float sumsq, float poly[16], float prf[64])
{
    float rn = 1.0f / fmaxf(sqrtf(sumsq), 1e-6f);
#pragma unroll
    for (int p = 0; p < 16; ++p) { float v = poly[p] * rn; poly[p] = v * v * 0.25f; }
    const float s0 = (float)QN0, s1 = (float)QN1;
    const float g0 = sqrtf(2.0f * (float)QN0), g1 = sqrtf(2.0f * (float)QN1);
    const float c0 = sqrtf((float)QW0) * 0.17677669529663687f;  // sqrt(w0)/sqrt(M)
    const float c1 = sqrtf((float)QW1) * 0.17677669529663687f;
#pragma unroll
    for (int m = 0; m < 32; ++m) {
        float z0 = prf[m]      * rn * g0 - s0;
        float z1 = prf[32 + m] * rn * g1 - s1;
        z0 = fminf(fmaxf(z0, -10.f), 10.f);
        z1 = fminf(fmaxf(z1, -10.f), 10.f);
        prf[m]      = expf(z0) * c0;
        prf[32 + m] = expf(z1) * c1;
    }
}

// one block: init slot/-1, Z/0, out/0, transpose anchors, then scatter label slots
__global__ void k_setup(const float* __restrict__ anchors, const int* __restrict__ labels,
                        int* __restrict__ slot, float* __restrict__ Z,
                        float* __restrict__ out, float* __restrict__ anct)
{
    int t = threadIdx.x;
    for (int i = t; i < 32768; i += 1024) slot[i] = -1;
    for (int i = t; i < 4096; i += 1024) Z[i] = 0.f;
    if (t == 0) out[0] = 0.f;
    for (int i = t; i < 2048; i += 1024) {
        int p = i & 15, d = i >> 4;
        anct[i] = anchors[p * 128 + d];
    }
    __syncthreads();
    for (int i = t; i < 2560; i += 1024) slot[max(labels[i], 0)] = i;
}

// fused: masked mean embedding -> LDS, then query features. One block per b.
__global__ void __launch_bounds__(256) k_embed_feat(const int* __restrict__ idx,
        const float* __restrict__ mask, const float* __restrict__ emb,
        const float* __restrict__ anct, const float* __restrict__ omega,
        float* __restrict__ polyq, float* __restrict__ prfq)
{
    __shared__ float xs[512];
    __shared__ float rnS[4];
    int b = blockIdx.x, t = threadIdx.x;

    float2 acc = make_float2(0.f, 0.f);
    float msum = 0.f;
#pragma unroll 8
    for (int s = 0; s < 64; ++s) {
        float mv = mask[b * 64 + s];
        const float2* row = (const float2*)(emb + (size_t)idx[b * 64 + s] * 512);
        float2 v = row[t];
        acc.x = fmaf(mv, v.x, acc.x);
        acc.y = fmaf(mv, v.y, acc.y);
        msum += mv;
    }
    float inv = 1.0f / fmaxf(msum, 1e-9f);
    xs[2 * t]     = acc.x * inv;
    xs[2 * t + 1] = acc.y * inv;
    __syncthreads();

    int w = t >> 6, lane = t & 63;
    {
        float v0 = xs[w * 128 + lane], v1 = xs[w * 128 + 64 + lane];
        float ss = fmaf(v0, v0, v1 * v1);
#pragma unroll
        for (int o = 1; o < 64; o <<= 1) ss += __shfl_xor(ss, o, 64);
        if (lane == 0) rnS[w] = 1.0f / fmaxf(sqrtf(ss), 1e-6f);
    }
    __syncthreads();

    const float s_[2] = {(float)QN0, (float)QN1};
    const float g_[2] = {sqrtf(2.0f * (float)QN0), sqrtf(2.0f * (float)QN1)};
    const float c_[2] = {sqrtf((float)QW0) * 0.17677669529663687f,
                         sqrtf((float)QW1) * 0.17677669529663687f};

    for (int tau = t; tau < 320; tau += 256) {
        int h = tau / 80, j = tau - h * 80;
        const float* xh = xs + h * 128;
        float a = 0.f;
        if (j < 16) {
            for (int d = 0; d < 128; ++d) a = fmaf(xh[d], anct[d * 16 + j], a);
            float v = a * rnS[h];
            polyq[(b * 4 + h) * 16 + j] = v * v * 0.25f;
        } else {
            int rj = j - 16, r = rj >> 5, m = rj & 31;
            const float* om = omega + ((size_t)(r * 4 + h) * 128) * 32 + m;
            for (int d = 0; d < 128; ++d) a = fmaf(xh[d], om[d * 32], a);
            float z = a * rnS[h] * g_[r] - s_[r];
            z = fminf(fmaxf(z, -10.f), 10.f);
            prfq[((b * 2 + r) * 4 + h) * 32 + m] = expf(z) * c_[r];
        }
    }
}

// dominant kernel: features for all 32768 labels, selective compact feature
// store, register-blocked Z matmul (thread owns 4p x 4m; one wave = full Z
// tile; waves split q; cross-wave reduce in LDS aliased over prfS).
__global__ void __launch_bounds__(256) k_labels(const float* __restrict__ ck,
                                                const float* __restrict__ anct,
                                                const float* __restrict__ omega,
                                                const int* __restrict__ slot,
                                                float* __restrict__ feat,
                                                float* __restrict__ Z)
{
    __shared__ float buf[11264];      // polyS [128][20] | prfS [128][68] (45 KB)
    float* polyS = buf;
    float* prfS  = buf + 2560;
    float* Zp    = buf + 2560;        // [4][1024] alias of prfS (after barrier)

    int t = threadIdx.x, w = t >> 6, lane = t & 63;
    int h = blockIdx.x & 3;
    int l = (blockIdx.x >> 2) * 256 + t;

    float sumsq = 0.f, poly[16] = {}, prf[64] = {};
    accum_feat(ck + (size_t)h * 128 * 32768 + l, 32768, anct, omega, h, sumsq, poly, prf);
    finalize_feat(sumsq, poly, prf);

    int s = slot[l];
    if (s >= 0) {
        float4* dst = (float4*)(feat + ((size_t)s * 4 + h) * 80);
#pragma unroll
        for (int j = 0; j < 4; ++j)
            dst[j] = make_float4(poly[4*j], poly[4*j+1], poly[4*j+2], poly[4*j+3]);
#pragma unroll
        for (int j = 0; j < 16; ++j)
            dst[4 + j] = make_float4(prf[4*j], prf[4*j+1], prf[4*j+2], prf[4*j+3]);
    }

    int r = lane >> 5, p4 = (lane >> 3) & 3, m4 = lane & 7;  // thread's Z block
    float zacc[4][4] = {};

#pragma unroll
    for (int bi = 0; bi < 2; ++bi) {
        if ((t >> 7) == bi) {         // stage this half's 128 labels
            int tl = t & 127;
#pragma unroll
            for (int p = 0; p < 16; ++p) polyS[tl * 20 + p] = poly[p];
            float4* dst = (float4*)(prfS + tl * 68);
#pragma unroll
            for (int j = 0; j < 16; ++j)
                dst[j] = make_float4(prf[4*j], prf[4*j+1], prf[4*j+2], prf[4*j+3]);
        }
        __syncthreads();
        int q0 = w * 32;              // waves split the 128 staged labels
        for (int q = 0; q < 32; ++q) {
            int row = q0 + q;
            float4 pv = *(const float4*)(polyS + row * 20 + p4 * 4);
            float4 fv = *(const float4*)(prfS + row * 68 + r * 32 + m4 * 4);
            zacc[0][0] = fmaf(pv.x, fv.x, zacc[0][0]);
            zacc[0][1] = fmaf(pv.x, fv.y, zacc[0][1]);
            zacc[0][2] = fmaf(pv.x, fv.z, zacc[0][2]);
            zacc[0][3] = fmaf(pv.x, fv.w, zacc[0][3]);
            zacc[1][0] = fmaf(pv.y, fv.x, zacc[1][0]);
            zacc[1][1] = fmaf(pv.y, fv.y, zacc[1][1]);
            zacc[1][2] = fmaf(pv.y, fv.z, zacc[1][2]);
            zacc[1][3] = fmaf(pv.y, fv.w, zacc[1][3]);
            zacc[2][0] = fmaf(pv.z, fv.x, zacc[2][0]);
            zacc[2][1] = fmaf(pv.z, fv.y, zacc[2][1]);
            zacc[2][2] = fmaf(pv.z, fv.z, zacc[2][2]);
            zacc[2][3] = fmaf(pv.z, fv.w, zacc[2][3]);
            zacc[3][0] = fmaf(pv.w, fv.x, zacc[3][0]);
            zacc[3][1] = fmaf(pv.w, fv.y, zacc[3][1]);
            zacc[3][2] = fmaf(pv.w, fv.z, zacc[3][2]);
            zacc[3][3] = fmaf(pv.w, fv.w, zacc[3][3]);
        }
        __syncthreads();
    }

    // wave partials -> LDS (contiguous per wave: conflict-free)
#pragma unroll
    for (int i = 0; i < 4; ++i) {
        float* zp = Zp + w * 1024 + (r * 16 + p4 * 4 + i) * 32 + m4 * 4;
        *(float4*)zp = make_float4(zacc[i][0], zacc[i][1], zacc[i][2], zacc[i][3]);
    }
    __syncthreads();

    int f = t * 4;                    // thread reduces 4 consecutive Z entries
    float4 a0 = *(const float4*)(Zp + f);
    float4 a1 = *(const float4*)(Zp + 1024 + f);
    float4 a2 = *(const float4*)(Zp + 2048 + f);
    float4 a3 = *(const float4*)(Zp + 3072 + f);
    float sx = a0.x + a1.x + a2.x + a3.x;
    float sy = a0.y + a1.y + a2.y + a3.y;
    float sz = a0.z + a1.z + a2.z + a3.z;
    float sw = a0.w + a1.w + a2.w + a3.w;
    // f encodes (r,p,m) as (r*16+p)*32+m ; global Z layout [r][h][p][m]
    float* zdst = Z + (f >> 9) * 2048 + h * 512 + (f & 511);
    atomicAdd(zdst + 0, sx);
    atomicAdd(zdst + 1, sy);
    atomicAdd(zdst + 2, sz);
    atomicAdd(zdst + 3, sw);
}

// fused denom + loss: one wave per batch row b
__global__ void k_final(const float* __restrict__ polyq, const float* __restrict__ prfq,
                        const float* __restrict__ Z, const int* __restrict__ labels,
                        const float* __restrict__ lmask, const int* __restrict__ slot,
                        const float* __restrict__ feat, float* __restrict__ out)
{
    int t = threadIdx.x, lane = t & 63;
    int b = blockIdx.x * 4 + (t >> 6);

    float acc = 0.f;
    for (int i = 0; i < 64; ++i) {
        int f = i * 64 + lane;                         // coalesced Z reads
        int m = f & 31, p = (f >> 5) & 15, hh = (f >> 9) & 3, r = f >> 11;
        float phi = polyq[(b * 4 + hh) * 16 + p] * prfq[((b * 2 + r) * 4 + hh) * 32 + m];
        acc = fmaf(phi, Z[f], acc);
    }
#pragma unroll
    for (int o = 1; o < 64; o <<= 1) acc += __shfl_xor(acc, o, 64);
    float logZb = logf(acc + 1e-6f);                   // all lanes hold the sum

    if (lane < 20) {                                   // lane = k*4 + h
        int k = lane >> 2, h = lane & 3;
        int l = max(labels[b * 5 + k], 0);
        int s = slot[l];
        const float4* f4 = (const float4*)(feat + ((size_t)s * 4 + h) * 80);
        const float* pq = polyq + (b * 4 + h) * 16;
        const float* q0 = prfq + ((b * 2 + 0) * 4 + h) * 32;
        const float* q1 = prfq + ((b * 2 + 1) * 4 + h) * 32;

        float pd = 0.f;
#pragma unroll
        for (int j = 0; j < 4; ++j) {
            float4 fp = f4[j];
            pd = fmaf(fp.x, pq[4*j+0], pd);
            pd = fmaf(fp.y, pq[4*j+1], pd);
            pd = fmaf(fp.z, pq[4*j+2], pd);
            pd = fmaf(fp.w, pq[4*j+3], pd);
        }
        float f0 = 0.f, f1 = 0.f;
#pragma unroll
        for (int j = 0; j < 8; ++j) {
            float4 fv = f4[4 + j];
            f0 = fmaf(fv.x, q0[4*j+0], f0);
            f0 = fmaf(fv.y, q0[4*j+1], f0);
            f0 = fmaf(fv.z, q0[4*j+2], f0);
            f0 = fmaf(fv.w, q0[4*j+3], f0);
            float4 fw = f4[12 + j];
            f1 = fmaf(fw.x, q1[4*j+0], f1);
            f1 = fmaf(fw.y, q1[4*j+1], f1);
            f1 = fmaf(fw.z, q1[4*j+2], f1);
            f1 = fmaf(fw.w, q1[4*j+3], f1);
        }
        float c = pd * (f0 + f1);
        c += __shfl_xor(c, 1, 64);                     // sum the 4 heads
        c += __shfl_xor(c, 2, 64);
        if (h == 0) {
            float val = (logf(c + 1e-6f) - logZb) * lmask[b * 5 + k];
            atomicAdd(out, val * (-1.0f / 512.0f));
        }
    }
}

extern "C" void kernel_launch(void* const* d_in, const int* in_sizes, int n_in,
                              void* d_out, int out_size, void* d_ws, size_t ws_size,
                              hipStream_t stream)
{
    const int*   indices = (const int*)  d_in[0];
    const float* mask    = (const float*)d_in[1];
    const int*   labels  = (const int*)  d_in[2];
    const float* lmask   = (const float*)d_in[3];
    const float* emb     = (const float*)d_in[4];
    const float* ck      = (const float*)d_in[5];   // [512][32768]
    const float* omega   = (const float*)d_in[6];   // [2][4][128][32]
    const float* anchors = (const float*)d_in[7];   // [16][128]
    float* ws  = (float*)d_ws;
    float* out = (float*)d_out;
    int*   slot = (int*)(ws + OFF_SLOT);
    float* feat = ws + OFF_FEAT;

    k_setup<<<1, 1024, 0, stream>>>(anchors, labels, slot, ws + OFF_Z, out, ws + OFF_ANCT);
    k_embed_feat<<<512, 256, 0, stream>>>(indices, mask, emb, ws + OFF_ANCT, omega,
                                          ws + OFF_POLYQ, ws + OFF_PRFQ);
    k_labels<<<512, 256, 0, stream>>>(ck, ws + OFF_ANCT, omega, slot, feat, ws + OFF_Z);
    k_final<<<128, 256, 0, stream>>>(ws + OFF_POLYQ, ws + OFF_PRFQ, ws + OFF_Z,
                                     labels, lmask, slot, feat, out);
}

// Round 4
// 415.022 us; speedup vs baseline: 1.1097x; 1.1097x over previous
//
#include <hip/hip_runtime.h>
#include <math.h>

// ---------------------------------------------------------------------------
// SLAY sampled-softmax loss on MI355X.
// H=4 heads, D=128, P=16 anchors, M=32 features, R=2 quad nodes, E=512.
// B=512, S=64, K=5, L=32768 labels, VOCAB=100000.
//
// Decomposition (never materialize phi matrices):
//   phi[n,(r,h,p,m)] = poly[n,h,p] * prf[r,n,h,m]
//   Z[r,h,p,m]  = sum_l poly_W[l,h,p]*prf_W[r,l,h,m]
//   denom[b]    = sum_f phi_q[b,f]*Z[f]
//   nums[b,k]   = sum_h (poly_W.poly_q)[h] * sum_r (prf_W.prf_q)[r,h]
//
// R3: k_labels restructured. Block = 64 labels x 1 head, 3 waves; wave w owns
// a 27-output slice; coefficients come from a pre-packed Wpack[h][128][84]
// via wave-uniform (readfirstlane) pointers -> scalar loads; 28 accs/thread
// (VGPR ~<96) for real occupancy. Z partials go to global scratch (no 204-VGPR
// register blocking, no hot atomics); k_zreduce sums them.
// ---------------------------------------------------------------------------

namespace {
constexpr double Cq  = 2.0 + 1e-6;
constexpr double QN0 = 0.5857864376269049  / Cq;   // laggauss(2) nodes / C
constexpr double QN1 = 3.414213562373095   / Cq;
constexpr double QW0 = 0.8535533905932738  / Cq;   // laggauss(2) weights / C
constexpr double QW1 = 0.14644660940672624 / Cq;

// workspace float offsets
constexpr size_t OFF_POLYQ = 0;                    // 512*4*16   [b][h][p]
constexpr size_t OFF_PRFQ  = 32768;                // 512*2*4*32 [b][r][h][m]
constexpr size_t OFF_Z     = OFF_PRFQ + 131072;    // 4096       [r][h][p][m]
constexpr size_t OFF_ANCT  = OFF_Z + 4096;         // 128*16 anchors^T [d][p]
constexpr size_t OFF_SLOT  = OFF_ANCT + 2048;      // 32768 ints: label->slot|-1
constexpr size_t OFF_FEAT  = OFF_SLOT + 32768;     // 2560*4*80 [slot][h][poly|prf]
constexpr size_t OFF_WPACK = OFF_FEAT + 819200;    // 4*128*84  [h][d][84 outputs]
constexpr size_t OFF_ZPART = OFF_WPACK + 43008;    // 2048*1024 per-block Z partials
}

// grid-parallel init: slot=-1, Z=0, out=0, anchors^T, Wpack
__global__ void k_setup_a(const float* __restrict__ anchors,
                          const float* __restrict__ omega,
                          int* __restrict__ slot, float* __restrict__ Z,
                          float* __restrict__ out, float* __restrict__ anct,
                          float* __restrict__ Wpack)
{
    int t = blockIdx.x * 256 + threadIdx.x;           // 64*256 = 16384 threads
    for (int i = t; i < 32768; i += 16384) slot[i] = -1;
    if (t < 4096) Z[t] = 0.f;
    if (t == 0) out[0] = 0.f;
    if (t < 2048) {                                   // anct[d][p]
        int p = t & 15, d = t >> 4;
        anct[t] = anchors[p * 128 + d];
    }
    for (int i = t; i < 4 * 128 * 84; i += 16384) {   // Wpack[h][d][o]
        int o = i % 84, hd = i / 84, d = hd & 127, h = hd >> 7;
        float v = 0.f;
        if (o < 16) v = anchors[o * 128 + d];
        else if (o < 80) {
            int r = (o - 16) >> 5, m = (o - 16) & 31;
            v = omega[(((r * 4 + h) * 128) + d) * 32 + m];
        }
        Wpack[i] = v;
    }
}

// slot scatter (must run after slot init -> separate dispatch)
__global__ void k_setup_b(const int* __restrict__ labels, int* __restrict__ slot)
{
    int i = blockIdx.x * 256 + threadIdx.x;
    if (i < 2560) slot[max(labels[i], 0)] = i;
}

// fused: masked mean embedding -> LDS, then query features. One block per b.
__global__ void __launch_bounds__(256) k_embed_feat(const int* __restrict__ idx,
        const float* __restrict__ mask, const float* __restrict__ emb,
        const float* __restrict__ anct, const float* __restrict__ omega,
        float* __restrict__ polyq, float* __restrict__ prfq)
{
    __shared__ float xs[512];
    __shared__ float rnS[4];
    int b = blockIdx.x, t = threadIdx.x;

    float2 acc = make_float2(0.f, 0.f);
    float msum = 0.f;
#pragma unroll 8
    for (int s = 0; s < 64; ++s) {
        float mv = mask[b * 64 + s];
        const float2* row = (const float2*)(emb + (size_t)idx[b * 64 + s] * 512);
        float2 v = row[t];
        acc.x = fmaf(mv, v.x, acc.x);
        acc.y = fmaf(mv, v.y, acc.y);
        msum += mv;
    }
    float inv = 1.0f / fmaxf(msum, 1e-9f);
    xs[2 * t]     = acc.x * inv;
    xs[2 * t + 1] = acc.y * inv;
    __syncthreads();

    int w = t >> 6, lane = t & 63;
    {
        float v0 = xs[w * 128 + lane], v1 = xs[w * 128 + 64 + lane];
        float ss = fmaf(v0, v0, v1 * v1);
#pragma unroll
        for (int o = 1; o < 64; o <<= 1) ss += __shfl_xor(ss, o, 64);
        if (lane == 0) rnS[w] = 1.0f / fmaxf(sqrtf(ss), 1e-6f);
    }
    __syncthreads();

    const float s_[2] = {(float)QN0, (float)QN1};
    const float g_[2] = {sqrtf(2.0f * (float)QN0), sqrtf(2.0f * (float)QN1)};
    const float c_[2] = {sqrtf((float)QW0) * 0.17677669529663687f,
                         sqrtf((float)QW1) * 0.17677669529663687f};

    for (int tau = t; tau < 320; tau += 256) {
        int h = tau / 80, j = tau - h * 80;
        const float* xh = xs + h * 128;
        float a = 0.f;
        if (j < 16) {
            for (int d = 0; d < 128; ++d) a = fmaf(xh[d], anct[d * 16 + j], a);
            float v = a * rnS[h];
            polyq[(b * 4 + h) * 16 + j] = v * v * 0.25f;
        } else {
            int rj = j - 16, r = rj >> 5, m = rj & 31;
            const float* om = omega + ((size_t)(r * 4 + h) * 128) * 32 + m;
            for (int d = 0; d < 128; ++d) a = fmaf(xh[d], om[d * 32], a);
            float z = a * rnS[h] * g_[r] - s_[r];
            z = fminf(fmaxf(z, -10.f), 10.f);
            prfq[((b * 2 + r) * 4 + h) * 32 + m] = expf(z) * c_[r];
        }
    }
}

// dominant kernel, restructured. Block = 64 labels x 1 head, 192 threads.
// Wave w computes outputs o = w*27..w*27+26 (81 total: 16 poly, 64 prf, sumsq)
// for its lane's label; coefficients are wave-uniform scalar loads from Wpack.
__global__ void __launch_bounds__(192) k_labels(const float* __restrict__ ck,
                                                const float* __restrict__ Wpack,
                                                const int* __restrict__ slot,
                                                float* __restrict__ feat,
                                                float* __restrict__ Zpart)
{
    __shared__ float ex[64 * 85];     // [label][85]: 0..80 outputs (stride 85: 2-way free)
    __shared__ int slS[64];

    int t = threadIdx.x, w = t >> 6, lane = t & 63;
    int bid = blockIdx.x;
    int g = bid >> 2, h = bid & 3;
    int l0 = g * 64;

    if (t < 64) slS[t] = slot[l0 + t];

    const float* xcol = ck + (size_t)h * 128 * 32768 + l0 + lane;
    int w27 = __builtin_amdgcn_readfirstlane(w * 27);
    const float* wrow = Wpack + (size_t)h * 128 * 84 + w27;

    float acc[27] = {};
    float sumsq = 0.f;
    for (int d = 0; d < 128; ++d) {
        float xv = xcol[(size_t)d * 32768];
        sumsq = fmaf(xv, xv, sumsq);
        const float* c = wrow + d * 84;
#pragma unroll
        for (int i = 0; i < 27; ++i) acc[i] = fmaf(xv, c[i], acc[i]);
    }

    // exchange to LDS: wave w writes its 27 cols; wave 2 also writes sumsq (col 80)
#pragma unroll
    for (int i = 0; i < 27; ++i) ex[lane * 85 + w27 + i] = acc[i];
    if (w == 2) ex[lane * 85 + 80] = sumsq;
    __syncthreads();

    // finalize in place: thread (l = t&63, part = t>>6) handles o = part*27 ..
    {
        int l = t & 63, part = t >> 6, o0 = part * 27;
        float rn = 1.0f / fmaxf(sqrtf(ex[l * 85 + 80]), 1e-6f);
        const float s_[2] = {(float)QN0, (float)QN1};
        const float g_[2] = {sqrtf(2.0f * (float)QN0), sqrtf(2.0f * (float)QN1)};
        const float c_[2] = {sqrtf((float)QW0) * 0.17677669529663687f,
                             sqrtf((float)QW1) * 0.17677669529663687f};
#pragma unroll
        for (int i = 0; i < 27; ++i) {
            int o = o0 + i;
            if (o >= 80) break;
            float v = ex[l * 85 + o];
            if (o < 16) {
                v = v * rn;
                v = v * v * 0.25f;
            } else {
                int r = (o - 16) >> 5;
                float z = v * rn * g_[r] - s_[r];
                z = fminf(fmaxf(z, -10.f), 10.f);
                v = expf(z) * c_[r];
            }
            ex[l * 85 + o] = v;
        }
    }
    __syncthreads();

    // selective compact feature store for the batch's positive labels
    for (int j = 0; j < 64; ++j) {
        int s = slS[j];
        if (s >= 0 && t < 80)
            feat[((size_t)s * 4 + h) * 80 + t] = ex[j * 85 + t];
    }

    // Z partial: thread (t<128) owns (r = t>>6, p0 = ((t>>3)&7)*2, m0 = (t&7)*4)
    if (t < 128) {
        int r = t >> 6, p0 = ((t >> 3) & 7) * 2, m0 = (t & 7) * 4;
        float z0[4] = {}, z1[4] = {};
        for (int j = 0; j < 64; ++j) {
            const float* row = ex + j * 85;
            float pa = row[p0], pb = row[p0 + 1];
            const float* pf = row + 16 + r * 32 + m0;
#pragma unroll
            for (int k = 0; k < 4; ++k) {
                float fv = pf[k];
                z0[k] = fmaf(pa, fv, z0[k]);
                z1[k] = fmaf(pb, fv, z1[k]);
            }
        }
        float* zp = Zpart + (size_t)bid * 1024;
#pragma unroll
        for (int k = 0; k < 4; ++k) {
            zp[(r * 16 + p0) * 32 + m0 + k]     = z0[k];
            zp[(r * 16 + p0 + 1) * 32 + m0 + k] = z1[k];
        }
    }
}

// sum the 2048 per-block Z partials into Z[r][h][p][m] (Z zeroed in setup_a)
__global__ void k_zreduce(const float* __restrict__ Zpart, float* __restrict__ Z)
{
    int tid = blockIdx.x * 256 + threadIdx.x;   // 128*256 = 32768
    int e = tid & 1023, h = (tid >> 10) & 3, chunk = tid >> 12;   // 8 chunks of 64 groups
    float sum = 0.f;
    int g0 = chunk * 64;
#pragma unroll 4
    for (int g = g0; g < g0 + 64; ++g)
        sum += Zpart[(size_t)((g << 2) | h) * 1024 + e];
    atomicAdd(&Z[(e >> 9) * 2048 + h * 512 + (e & 511)], sum);
}

// fused denom + loss: one wave per batch row b
__global__ void k_final(const float* __restrict__ polyq, const float* __restrict__ prfq,
                        const float* __restrict__ Z, const int* __restrict__ labels,
                        const float* __restrict__ lmask, const int* __restrict__ slot,
                        const float* __restrict__ feat, float* __restrict__ out)
{
    int t = threadIdx.x, lane = t & 63;
    int b = blockIdx.x * 4 + (t >> 6);

    float acc = 0.f;
    for (int i = 0; i < 64; ++i) {
        int f = i * 64 + lane;                         // coalesced Z reads
        int m = f & 31, p = (f >> 5) & 15, hh = (f >> 9) & 3, r = f >> 11;
        float phi = polyq[(b * 4 + hh) * 16 + p] * prfq[((b * 2 + r) * 4 + hh) * 32 + m];
        acc = fmaf(phi, Z[f], acc);
    }
#pragma unroll
    for (int o = 1; o < 64; o <<= 1) acc += __shfl_xor(acc, o, 64);
    float logZb = logf(acc + 1e-6f);                   // all lanes hold the sum

    if (lane < 20) {                                   // lane = k*4 + h
        int k = lane >> 2, h = lane & 3;
        int l = max(labels[b * 5 + k], 0);
        int s = slot[l];
        const float4* f4 = (const float4*)(feat + ((size_t)s * 4 + h) * 80);
        const float* pq = polyq + (b * 4 + h) * 16;
        const float* q0 = prfq + ((b * 2 + 0) * 4 + h) * 32;
        const float* q1 = prfq + ((b * 2 + 1) * 4 + h) * 32;

        float pd = 0.f;
#pragma unroll
        for (int j = 0; j < 4; ++j) {
            float4 fp = f4[j];
            pd = fmaf(fp.x, pq[4*j+0], pd);
            pd = fmaf(fp.y, pq[4*j+1], pd);
            pd = fmaf(fp.z, pq[4*j+2], pd);
            pd = fmaf(fp.w, pq[4*j+3], pd);
        }
        float f0 = 0.f, f1 = 0.f;
#pragma unroll
        for (int j = 0; j < 8; ++j) {
            float4 fv = f4[4 + j];
            f0 = fmaf(fv.x, q0[4*j+0], f0);
            f0 = fmaf(fv.y, q0[4*j+1], f0);
            f0 = fmaf(fv.z, q0[4*j+2], f0);
            f0 = fmaf(fv.w, q0[4*j+3], f0);
            float4 fw = f4[12 + j];
            f1 = fmaf(fw.x, q1[4*j+0], f1);
            f1 = fmaf(fw.y, q1[4*j+1], f1);
            f1 = fmaf(fw.z, q1[4*j+2], f1);
            f1 = fmaf(fw.w, q1[4*j+3], f1);
        }
        float c = pd * (f0 + f1);
        c += __shfl_xor(c, 1, 64);                     // sum the 4 heads
        c += __shfl_xor(c, 2, 64);
        if (h == 0) {
            float val = (logf(c + 1e-6f) - logZb) * lmask[b * 5 + k];
            atomicAdd(out, val * (-1.0f / 512.0f));
        }
    }
}

extern "C" void kernel_launch(void* const* d_in, const int* in_sizes, int n_in,
                              void* d_out, int out_size, void* d_ws, size_t ws_size,
                              hipStream_t stream)
{
    const int*   indices = (const int*)  d_in[0];
    const float* mask    = (const float*)d_in[1];
    const int*   labels  = (const int*)  d_in[2];
    const float* lmask   = (const float*)d_in[3];
    const float* emb     = (const float*)d_in[4];
    const float* ck      = (const float*)d_in[5];   // [512][32768]
    const float* omega   = (const float*)d_in[6];   // [2][4][128][32]
    const float* anchors = (const float*)d_in[7];   // [16][128]
    float* ws  = (float*)d_ws;
    float* out = (float*)d_out;
    int*   slot = (int*)(ws + OFF_SLOT);

    k_setup_a<<<64, 256, 0, stream>>>(anchors, omega, slot, ws + OFF_Z, out,
                                      ws + OFF_ANCT, ws + OFF_WPACK);
    k_setup_b<<<10, 256, 0, stream>>>(labels, slot);
    k_embed_feat<<<512, 256, 0, stream>>>(indices, mask, emb, ws + OFF_ANCT, omega,
                                          ws + OFF_POLYQ, ws + OFF_PRFQ);
    k_labels<<<2048, 192, 0, stream>>>(ck, ws + OFF_WPACK, slot,
                                       ws + OFF_FEAT, ws + OFF_ZPART);
    k_zreduce<<<128, 256, 0, stream>>>(ws + OFF_ZPART, ws + OFF_Z);
    k_final<<<128, 256, 0, stream>>>(ws + OFF_POLYQ, ws + OFF_PRFQ, ws + OFF_Z,
                                     labels, lmask, slot, ws + OFF_FEAT, out);
}

// Round 5
// 392.791 us; speedup vs baseline: 1.1726x; 1.0566x over previous
//
#include <hip/hip_runtime.h>
#include <math.h>

// ---------------------------------------------------------------------------
// SLAY sampled-softmax loss on MI355X.
// H=4 heads, D=128, P=16 anchors, M=32 features, R=2 quad nodes, E=512.
// B=512, S=64, K=5, L=32768 labels, VOCAB=100000.
//
// Decomposition (never materialize phi matrices):
//   phi[n,(r,h,p,m)] = poly[n,h,p] * prf[r,n,h,m]
//   Z[r,h,p,m]  = sum_l poly_W[l,h,p]*prf_W[r,l,h,m]
//   denom[b]    = sum_f phi_q[b,f]*Z[f]
//   nums[b,k]   = sum_h (poly_W.poly_q)[h] * sum_r (prf_W.prf_q)[r,h]
//
// R4: k_labels stages its 64x128 ck tile into LDS once (coalesced streaming,
// then free broadcast reads), 4 waves x 21 outputs from zero-padded
// Wpack[h][d][84] via wave-uniform scalar loads; exchange buffer aliases the
// x-tile. d-loop is pure LDS+SALU+VALU -> should sit near the VALU floor.
// ---------------------------------------------------------------------------

namespace {
constexpr double Cq  = 2.0 + 1e-6;
constexpr double QN0 = 0.5857864376269049  / Cq;   // laggauss(2) nodes / C
constexpr double QN1 = 3.414213562373095   / Cq;
constexpr double QW0 = 0.8535533905932738  / Cq;   // laggauss(2) weights / C
constexpr double QW1 = 0.14644660940672624 / Cq;

// workspace float offsets
constexpr size_t OFF_POLYQ = 0;                    // 512*4*16   [b][h][p]
constexpr size_t OFF_PRFQ  = 32768;                // 512*2*4*32 [b][r][h][m]
constexpr size_t OFF_Z     = OFF_PRFQ + 131072;    // 4096       [r][h][p][m]
constexpr size_t OFF_ANCT  = OFF_Z + 4096;         // 128*16 anchors^T [d][p]
constexpr size_t OFF_SLOT  = OFF_ANCT + 2048;      // 32768 ints: label->slot|-1
constexpr size_t OFF_FEAT  = OFF_SLOT + 32768;     // 2560*4*80 [slot][h][poly|prf]
constexpr size_t OFF_WPACK = OFF_FEAT + 819200;    // 4*128*84  [h][d][84 outputs]
constexpr size_t OFF_ZPART = OFF_WPACK + 43008;    // 2048*1024 per-block Z partials
}

// grid-parallel init: slot=-1, Z=0, out=0, anchors^T, Wpack (o>=80 zero pad)
__global__ void k_setup_a(const float* __restrict__ anchors,
                          const float* __restrict__ omega,
                          int* __restrict__ slot, float* __restrict__ Z,
                          float* __restrict__ out, float* __restrict__ anct,
                          float* __restrict__ Wpack)
{
    int t = blockIdx.x * 256 + threadIdx.x;           // 64*256 = 16384 threads
    for (int i = t; i < 32768; i += 16384) slot[i] = -1;
    if (t < 4096) Z[t] = 0.f;
    if (t == 0) out[0] = 0.f;
    if (t < 2048) {                                   // anct[d][p]
        int p = t & 15, d = t >> 4;
        anct[t] = anchors[p * 128 + d];
    }
    for (int i = t; i < 4 * 128 * 84; i += 16384) {   // Wpack[h][d][o]
        int o = i % 84, hd = i / 84, d = hd & 127, h = hd >> 7;
        float v = 0.f;
        if (o < 16) v = anchors[o * 128 + d];
        else if (o < 80) {
            int r = (o - 16) >> 5, m = (o - 16) & 31;
            v = omega[(((r * 4 + h) * 128) + d) * 32 + m];
        }
        Wpack[i] = v;
    }
}

// slot scatter (must run after slot init -> separate dispatch)
__global__ void k_setup_b(const int* __restrict__ labels, int* __restrict__ slot)
{
    int i = blockIdx.x * 256 + threadIdx.x;
    if (i < 2560) slot[max(labels[i], 0)] = i;
}

// fused: masked mean embedding -> LDS, then query features. One block per b.
__global__ void __launch_bounds__(256) k_embed_feat(const int* __restrict__ idx,
        const float* __restrict__ mask, const float* __restrict__ emb,
        const float* __restrict__ anct, const float* __restrict__ omega,
        float* __restrict__ polyq, float* __restrict__ prfq)
{
    __shared__ float xs[512];
    __shared__ float rnS[4];
    int b = blockIdx.x, t = threadIdx.x;

    float2 acc = make_float2(0.f, 0.f);
    float msum = 0.f;
#pragma unroll 8
    for (int s = 0; s < 64; ++s) {
        float mv = mask[b * 64 + s];
        const float2* row = (const float2*)(emb + (size_t)idx[b * 64 + s] * 512);
        float2 v = row[t];
        acc.x = fmaf(mv, v.x, acc.x);
        acc.y = fmaf(mv, v.y, acc.y);
        msum += mv;
    }
    float inv = 1.0f / fmaxf(msum, 1e-9f);
    xs[2 * t]     = acc.x * inv;
    xs[2 * t + 1] = acc.y * inv;
    __syncthreads();

    int w = t >> 6, lane = t & 63;
    {
        float v0 = xs[w * 128 + lane], v1 = xs[w * 128 + 64 + lane];
        float ss = fmaf(v0, v0, v1 * v1);
#pragma unroll
        for (int o = 1; o < 64; o <<= 1) ss += __shfl_xor(ss, o, 64);
        if (lane == 0) rnS[w] = 1.0f / fmaxf(sqrtf(ss), 1e-6f);
    }
    __syncthreads();

    const float s_[2] = {(float)QN0, (float)QN1};
    const float g_[2] = {sqrtf(2.0f * (float)QN0), sqrtf(2.0f * (float)QN1)};
    const float c_[2] = {sqrtf((float)QW0) * 0.17677669529663687f,
                         sqrtf((float)QW1) * 0.17677669529663687f};

    for (int tau = t; tau < 320; tau += 256) {
        int h = tau / 80, j = tau - h * 80;
        const float* xh = xs + h * 128;
        float a = 0.f;
        if (j < 16) {
            for (int d = 0; d < 128; ++d) a = fmaf(xh[d], anct[d * 16 + j], a);
            float v = a * rnS[h];
            polyq[(b * 4 + h) * 16 + j] = v * v * 0.25f;
        } else {
            int rj = j - 16, r = rj >> 5, m = rj & 31;
            const float* om = omega + ((size_t)(r * 4 + h) * 128) * 32 + m;
            for (int d = 0; d < 128; ++d) a = fmaf(xh[d], om[d * 32], a);
            float z = a * rnS[h] * g_[r] - s_[r];
            z = fminf(fmaxf(z, -10.f), 10.f);
            prfq[((b * 2 + r) * 4 + h) * 32 + m] = expf(z) * c_[r];
        }
    }
}

// dominant kernel. Block = 64 labels x 1 head, 256 threads (4 waves).
// Phase 1: stage ck tile [128 d][64 labels] into LDS (coalesced 256 B/wave).
// Phase 2: wave w computes outputs o = w*21..w*21+20 (zero-padded to 84) for
// its lane's label; coefficients are wave-uniform scalar loads from Wpack;
// x comes from LDS broadcast-row reads (2-way aliasing = free).
// Phase 3: exchange (aliases x tile), finalize, feat store, Z partial.
__global__ void __launch_bounds__(256) k_labels(const float* __restrict__ ck,
                                                const float* __restrict__ Wpack,
                                                const int* __restrict__ slot,
                                                float* __restrict__ feat,
                                                float* __restrict__ Zpart)
{
    __shared__ float xs[8192];        // [d][64]; aliased by ex[64][85] later
    __shared__ int slS[64];
    float* ex = xs;

    int t = threadIdx.x, w = t >> 6, lane = t & 63;
    int bid = blockIdx.x;
    int g = bid >> 2, h = bid & 3;
    int l0 = g * 64;

    if (t < 64) slS[t] = slot[l0 + t];

    // ---- phase 1: stage x tile ----
    {
        const float* src = ck + (size_t)h * 128 * 32768 + l0;
#pragma unroll
        for (int k = 0; k < 32; ++k) {
            int idx = k * 256 + t;                 // d = k*4 + w, lab = lane
            int d = idx >> 6, lab = idx & 63;
            xs[idx] = src[(size_t)d * 32768 + lab];
        }
    }
    __syncthreads();

    // ---- phase 2: accumulate 21 outputs + sumsq ----
    int o0u = __builtin_amdgcn_readfirstlane(w * 21);
    const float* wrow = Wpack + (size_t)h * 128 * 84 + o0u;
    float acc[21] = {};
    float sumsq = 0.f;
    for (int d = 0; d < 128; ++d) {
        float xv = xs[d * 64 + lane];
        sumsq = fmaf(xv, xv, sumsq);
        const float* c = wrow + d * 84;
#pragma unroll
        for (int i = 0; i < 21; ++i) acc[i] = fmaf(xv, c[i], acc[i]);
    }
    __syncthreads();                  // all waves done reading xs

    // ---- phase 3: exchange into ex[label][85] (aliases xs) ----
#pragma unroll
    for (int i = 0; i < 21; ++i) {
        int o = o0u + i;
        if (o < 80) ex[lane * 85 + o] = acc[i];
    }
    if (w == 3) ex[lane * 85 + 80] = sumsq;
    __syncthreads();

    // finalize in place: thread (l = t&63, part = t>>6) handles 20 outputs
    {
        int l = t & 63, part = t >> 6, o0 = part * 20;
        float rn = 1.0f / fmaxf(sqrtf(ex[l * 85 + 80]), 1e-6f);
        const float s_[2] = {(float)QN0, (float)QN1};
        const float g_[2] = {sqrtf(2.0f * (float)QN0), sqrtf(2.0f * (float)QN1)};
        const float c_[2] = {sqrtf((float)QW0) * 0.17677669529663687f,
                             sqrtf((float)QW1) * 0.17677669529663687f};
#pragma unroll
        for (int i = 0; i < 20; ++i) {
            int o = o0 + i;
            float v = ex[l * 85 + o];
            if (o < 16) {
                v = v * rn;
                v = v * v * 0.25f;
            } else {
                int r = (o - 16) >> 5;
                float z = v * rn * g_[r] - s_[r];
                z = fminf(fmaxf(z, -10.f), 10.f);
                v = expf(z) * c_[r];
            }
            ex[l * 85 + o] = v;
        }
    }
    __syncthreads();

    // selective compact feature store for the batch's positive labels
    for (int j = 0; j < 64; ++j) {
        int s = slS[j];
        if (s >= 0 && t < 80)
            feat[((size_t)s * 4 + h) * 80 + t] = ex[j * 85 + t];
    }

    // Z partial: thread (t<128) owns (r = t>>6, p0 = ((t>>3)&7)*2, m0 = (t&7)*4)
    if (t < 128) {
        int r = t >> 6, p0 = ((t >> 3) & 7) * 2, m0 = (t & 7) * 4;
        float z0[4] = {}, z1[4] = {};
        for (int j = 0; j < 64; ++j) {
            const float* row = ex + j * 85;
            float pa = row[p0], pb = row[p0 + 1];
            const float* pf = row + 16 + r * 32 + m0;
#pragma unroll
            for (int k = 0; k < 4; ++k) {
                float fv = pf[k];
                z0[k] = fmaf(pa, fv, z0[k]);
                z1[k] = fmaf(pb, fv, z1[k]);
            }
        }
        float* zp = Zpart + (size_t)bid * 1024;
#pragma unroll
        for (int k = 0; k < 4; ++k) {
            zp[(r * 16 + p0) * 32 + m0 + k]     = z0[k];
            zp[(r * 16 + p0 + 1) * 32 + m0 + k] = z1[k];
        }
    }
}

// sum the 2048 per-block Z partials into Z[r][h][p][m] (Z zeroed in setup_a)
__global__ void k_zreduce(const float* __restrict__ Zpart, float* __restrict__ Z)
{
    int tid = blockIdx.x * 256 + threadIdx.x;   // 128*256 = 32768
    int e = tid & 1023, h = (tid >> 10) & 3, chunk = tid >> 12;   // 8 chunks of 64 groups
    float sum = 0.f;
    int g0 = chunk * 64;
#pragma unroll 4
    for (int g = g0; g < g0 + 64; ++g)
        sum += Zpart[(size_t)((g << 2) | h) * 1024 + e];
    atomicAdd(&Z[(e >> 9) * 2048 + h * 512 + (e & 511)], sum);
}

// fused denom + loss: one wave per batch row b
__global__ void k_final(const float* __restrict__ polyq, const float* __restrict__ prfq,
                        const float* __restrict__ Z, const int* __restrict__ labels,
                        const float* __restrict__ lmask, const int* __restrict__ slot,
                        const float* __restrict__ feat, float* __restrict__ out)
{
    int t = threadIdx.x, lane = t & 63;
    int b = blockIdx.x * 4 + (t >> 6);

    float acc = 0.f;
    for (int i = 0; i < 64; ++i) {
        int f = i * 64 + lane;                         // coalesced Z reads
        int m = f & 31, p = (f >> 5) & 15, hh = (f >> 9) & 3, r = f >> 11;
        float phi = polyq[(b * 4 + hh) * 16 + p] * prfq[((b * 2 + r) * 4 + hh) * 32 + m];
        acc = fmaf(phi, Z[f], acc);
    }
#pragma unroll
    for (int o = 1; o < 64; o <<= 1) acc += __shfl_xor(acc, o, 64);
    float logZb = logf(acc + 1e-6f);                   // all lanes hold the sum

    if (lane < 20) {                                   // lane = k*4 + h
        int k = lane >> 2, h = lane & 3;
        int l = max(labels[b * 5 + k], 0);
        int s = slot[l];
        const float4* f4 = (const float4*)(feat + ((size_t)s * 4 + h) * 80);
        const float* pq = polyq + (b * 4 + h) * 16;
        const float* q0 = prfq + ((b * 2 + 0) * 4 + h) * 32;
        const float* q1 = prfq + ((b * 2 + 1) * 4 + h) * 32;

        float pd = 0.f;
#pragma unroll
        for (int j = 0; j < 4; ++j) {
            float4 fp = f4[j];
            pd = fmaf(fp.x, pq[4*j+0], pd);
            pd = fmaf(fp.y, pq[4*j+1], pd);
            pd = fmaf(fp.z, pq[4*j+2], pd);
            pd = fmaf(fp.w, pq[4*j+3], pd);
        }
        float f0 = 0.f, f1 = 0.f;
#pragma unroll
        for (int j = 0; j < 8; ++j) {
            float4 fv = f4[4 + j];
            f0 = fmaf(fv.x, q0[4*j+0], f0);
            f0 = fmaf(fv.y, q0[4*j+1], f0);
            f0 = fmaf(fv.z, q0[4*j+2], f0);
            f0 = fmaf(fv.w, q0[4*j+3], f0);
            float4 fw = f4[12 + j];
            f1 = fmaf(fw.x, q1[4*j+0], f1);
            f1 = fmaf(fw.y, q1[4*j+1], f1);
            f1 = fmaf(fw.z, q1[4*j+2], f1);
            f1 = fmaf(fw.w, q1[4*j+3], f1);
        }
        float c = pd * (f0 + f1);
        c += __shfl_xor(c, 1, 64);                     // sum the 4 heads
        c += __shfl_xor(c, 2, 64);
        if (h == 0) {
            float val = (logf(c + 1e-6f) - logZb) * lmask[b * 5 + k];
            atomicAdd(out, val * (-1.0f / 512.0f));
        }
    }
}

extern "C" void kernel_launch(void* const* d_in, const int* in_sizes, int n_in,
                              void* d_out, int out_size, void* d_ws, size_t ws_size,
                              hipStream_t stream)
{
    const int*   indices = (const int*)  d_in[0];
    const float* mask    = (const float*)d_in[1];
    const int*   labels  = (const int*)  d_in[2];
    const float* lmask   = (const float*)d_in[3];
    const float* emb     = (const float*)d_in[4];
    const float* ck      = (const float*)d_in[5];   // [512][32768]
    const float* omega   = (const float*)d_in[6];   // [2][4][128][32]
    const float* anchors = (const float*)d_in[7];   // [16][128]
    float* ws  = (float*)d_ws;
    float* out = (float*)d_out;
    int*   slot = (int*)(ws + OFF_SLOT);

    k_setup_a<<<64, 256, 0, stream>>>(anchors, omega, slot, ws + OFF_Z, out,
                                      ws + OFF_ANCT, ws + OFF_WPACK);
    k_setup_b<<<10, 256, 0, stream>>>(labels, slot);
    k_embed_feat<<<512, 256, 0, stream>>>(indices, mask, emb, ws + OFF_ANCT, omega,
                                          ws + OFF_POLYQ, ws + OFF_PRFQ);
    k_labels<<<2048, 256, 0, stream>>>(ck, ws + OFF_WPACK, slot,
                                       ws + OFF_FEAT, ws + OFF_ZPART);
    k_zreduce<<<128, 256, 0, stream>>>(ws + OFF_ZPART, ws + OFF_Z);
    k_final<<<128, 256, 0, stream>>>(ws + OFF_POLYQ, ws + OFF_PRFQ, ws + OFF_Z,
                                     labels, lmask, slot, ws + OFF_FEAT, out);
}